// Round 2
// baseline (15786.353 us; speedup 1.0000x reference)
//
#include <hip/hip_runtime.h>

#define B_ 128
#define T_ 80
#define AD 32
#define ZD 64
#define KD 16
#define S8 68   // stride for 64-col matrices (float4-aligned rows, 2-way banks)
#define S4 34   // stride for 32-col matrices (float2-aligned)
#define S5 65   // stride for 64-col scalar-access matrices

// acc[2][4] += op(Pa) @ Qb, rows (r2,r2+1), cols c4..c4+3. B rows must be 16B aligned.
template<int KL, int AS, int BS, bool ATRANS>
__device__ __forceinline__ void mm64(const float* __restrict__ Pa, const float* __restrict__ Qb,
                                     float acc[2][4], int r2, int c4)
{
#pragma unroll 8
    for (int k = 0; k < KL; k++) {
        float aA, aB;
        if (ATRANS) { aA = Pa[k * AS + r2];   aB = Pa[k * AS + r2 + 1]; }
        else        { aA = Pa[r2 * AS + k];   aB = Pa[(r2 + 1) * AS + k]; }
        const float4 bv = *(const float4*)&Qb[k * BS + c4];
        acc[0][0] += aA * bv.x; acc[0][1] += aA * bv.y; acc[0][2] += aA * bv.z; acc[0][3] += aA * bv.w;
        acc[1][0] += aB * bv.x; acc[1][1] += aB * bv.y; acc[1][2] += aB * bv.z; acc[1][3] += aB * bv.w;
    }
}

__global__ __launch_bounds__(512, 2)
void kvae_kernel(const float* __restrict__ obs, const float* __restrict__ logits,
                 const float* __restrict__ AK, const float* __restrict__ CK,
                 float* __restrict__ out)
{
    // ---- LDS: separate objects so the compiler can disambiguate (no false lgkmcnt serialization)
    __shared__ __align__(16) float W[T_ * KD];      // softmax weights
    __shared__ __align__(16) float Am[ZD * S8];     // A(t+1)
    __shared__ __align__(16) float At[ZD * S8];     // A(t+1)^T
    __shared__ __align__(16) float SP[ZD * S8];     // sig_p / spn
    __shared__ __align__(16) float SF[ZD * S8];     // sig_f
    __shared__ __align__(16) float Mm[ZD * S8];     // M / V scratch
    __shared__ __align__(16) float PoolA[8704];     // fwd: T1,CM,CT,TI | bwd: LB,X
    __shared__ __align__(16) float PoolB[8320];     // fwd: SS,Z        | bwd: T6,SG
    __shared__ __align__(16) float Lc[64];          // chol column broadcast
    __shared__ __align__(16) float invd[64];        // 1/L_ii
    __shared__ __align__(16) float y_s[32];
    __shared__ __align__(16) float mup[64];
    __shared__ __align__(16) float err[32];
    __shared__ __align__(16) float e2[32];
    __shared__ __align__(16) float muf[64];
    __shared__ __align__(16) float mus[64];
    __shared__ __align__(16) float mpn[64];
    __shared__ __align__(16) float dv[64];

    // forward aliases
    float* T1 = PoolA;             // [32][68]
    float* CM = PoolA + 2176;      // [32][68]
    float* CT = PoolA + 4352;      // [64][34]
    float* TI = PoolA + 6528;      // [32][34]  L^-1 (32)
    float* SS = PoolB;             // [32][34]  S -> chol L
    float* Zm = PoolB + 1088;      // [32][68]  Z = L^-1 T1
    // backward aliases
    float* LB = PoolA;             // [64][68]  chol L -> Y
    float* X_ = PoolA + 4352;      // [64][68]  X = J^T
    float* T6 = PoolB;             // [64][65]  L^-1 (64)
    float* SG = PoolB + 4160;      // [64][65]  sig_s carry

    const int tid  = threadIdx.x;
    const int b    = blockIdx.x;
    const int lane = tid & 63;

    const int r16 = tid >> 4;        // 0..31
    const int cg  = tid & 15;        // 0..15
    const int c4  = cg << 2;         // 0..60
    const int c2  = cg << 1;         // 0..30
    const int r2  = r16 << 1;        // 0..62

    const float* obs_b = obs    + (size_t)b * T_ * AD;
    const float* lg_b  = logits + (size_t)b * T_ * KD;
    float* omu = out + (size_t)b * T_ * ZD;
    float* osg = out + (size_t)B_ * T_ * ZD + (size_t)b * T_ * ZD * ZD;
    const float4* AK4 = (const float4*)AK;
    const float4* CK4 = (const float4*)CK;

    // ---- full-block mixers
    auto mixA_full = [&](int tt) {
#pragma unroll
        for (int rr = 0; rr < 2; rr++) {
            int r = r2 + rr;
            float4 a = make_float4(0.f, 0.f, 0.f, 0.f);
#pragma unroll
            for (int k = 0; k < KD; k++) {
                float wk = W[tt * KD + k];
                float4 v = AK4[k * 1024 + r * 16 + cg];
                a.x += wk * v.x; a.y += wk * v.y; a.z += wk * v.z; a.w += wk * v.w;
            }
            *(float4*)&Am[r * S8 + c4] = a;
            At[(c4 + 0) * S8 + r] = a.x; At[(c4 + 1) * S8 + r] = a.y;
            At[(c4 + 2) * S8 + r] = a.z; At[(c4 + 3) * S8 + r] = a.w;
        }
    };
    auto mixC_full = [&](int tt) {
        float4 a = make_float4(0.f, 0.f, 0.f, 0.f);
#pragma unroll
        for (int k = 0; k < KD; k++) {
            float wk = W[tt * KD + k];
            float4 v = CK4[k * 512 + r16 * 16 + cg];
            a.x += wk * v.x; a.y += wk * v.y; a.z += wk * v.z; a.w += wk * v.w;
        }
        *(float4*)&CM[r16 * S8 + c4] = a;
        CT[(c4 + 0) * S4 + r16] = a.x; CT[(c4 + 1) * S4 + r16] = a.y;
        CT[(c4 + 2) * S4 + r16] = a.z; CT[(c4 + 3) * S4 + r16] = a.w;
    };
    // partial mixers (run during stage3 by idle waves)
    auto mixA_part = [&](int tt) {       // threads 256..511
        int u = tid & 255; int r = u >> 2; int q = u & 3;
        float4 a0 = make_float4(0,0,0,0), a1 = a0, a2 = a0, a3 = a0;
#pragma unroll
        for (int k = 0; k < KD; k++) {
            float wk = W[tt * KD + k];
            const float4* s = AK4 + k * 1024 + r * 16 + q * 4;
            float4 v0 = s[0], v1 = s[1], v2 = s[2], v3 = s[3];
            a0.x += wk*v0.x; a0.y += wk*v0.y; a0.z += wk*v0.z; a0.w += wk*v0.w;
            a1.x += wk*v1.x; a1.y += wk*v1.y; a1.z += wk*v1.z; a1.w += wk*v1.w;
            a2.x += wk*v2.x; a2.y += wk*v2.y; a2.z += wk*v2.z; a2.w += wk*v2.w;
            a3.x += wk*v3.x; a3.y += wk*v3.y; a3.z += wk*v3.z; a3.w += wk*v3.w;
        }
        float4 acc[4] = {a0, a1, a2, a3};
#pragma unroll
        for (int j = 0; j < 4; j++) {
            int c0 = q * 16 + j * 4;
            *(float4*)&Am[r * S8 + c0] = acc[j];
            At[(c0 + 0) * S8 + r] = acc[j].x; At[(c0 + 1) * S8 + r] = acc[j].y;
            At[(c0 + 2) * S8 + r] = acc[j].z; At[(c0 + 3) * S8 + r] = acc[j].w;
        }
    };
    auto mixC_part = [&](int tt) {       // threads 128..255
        int u = tid & 127; int r = u >> 2; int q = u & 3;
        float4 a0 = make_float4(0,0,0,0), a1 = a0, a2 = a0, a3 = a0;
#pragma unroll
        for (int k = 0; k < KD; k++) {
            float wk = W[tt * KD + k];
            const float4* s = CK4 + k * 512 + r * 16 + q * 4;
            float4 v0 = s[0], v1 = s[1], v2 = s[2], v3 = s[3];
            a0.x += wk*v0.x; a0.y += wk*v0.y; a0.z += wk*v0.z; a0.w += wk*v0.w;
            a1.x += wk*v1.x; a1.y += wk*v1.y; a1.z += wk*v1.z; a1.w += wk*v1.w;
            a2.x += wk*v2.x; a2.y += wk*v2.y; a2.z += wk*v2.z; a2.w += wk*v2.w;
            a3.x += wk*v3.x; a3.y += wk*v3.y; a3.z += wk*v3.z; a3.w += wk*v3.w;
        }
        float4 acc[4] = {a0, a1, a2, a3};
#pragma unroll
        for (int j = 0; j < 4; j++) {
            int c0 = q * 16 + j * 4;
            *(float4*)&CM[r * S8 + c0] = acc[j];
            CT[(c0 + 0) * S4 + r] = acc[j].x; CT[(c0 + 1) * S4 + r] = acc[j].y;
            CT[(c0 + 2) * S4 + r] = acc[j].z; CT[(c0 + 3) * S4 + r] = acc[j].w;
        }
    };

    // ---- prologue
    if (tid < T_) {
        float l[KD]; float mx = -1e30f;
#pragma unroll
        for (int k = 0; k < KD; k++) { l[k] = lg_b[tid * KD + k]; mx = fmaxf(mx, l[k]); }
        float s = 0.f;
#pragma unroll
        for (int k = 0; k < KD; k++) { l[k] = expf(l[k] - mx); s += l[k]; }
        float inv = 1.0f / s;
#pragma unroll
        for (int k = 0; k < KD; k++) W[tid * KD + k] = l[k] * inv;
    }
#pragma unroll
    for (int rr = 0; rr < 2; rr++) {
        int r = r2 + rr;
#pragma unroll
        for (int j = 0; j < 4; j++) SP[r * S8 + c4 + j] = (r == c4 + j) ? 20.0f : 0.0f;
    }
    if (tid < ZD) mup[tid] = 0.0f;
    __syncthreads();
    mixC_full(0);
    __syncthreads();

    // ================= FORWARD FILTER =================
    for (int t = 0; t < T_; t++) {
        if (t < T_ - 1) mixA_full(t + 1);
        if (tid < AD) y_s[tid] = obs_b[t * AD + tid];
        // stage1: T1 = CM @ SP   [32x64] k=64
        {
            float a0 = 0, a1 = 0, a2 = 0, a3 = 0;
            const float* pa = CM + r16 * S8;
#pragma unroll 8
            for (int k = 0; k < ZD; k++) {
                float a = pa[k];
                float4 bv = *(const float4*)&SP[k * S8 + c4];
                a0 += a * bv.x; a1 += a * bv.y; a2 += a * bv.z; a3 += a * bv.w;
            }
            T1[r16 * S8 + c4 + 0] = a0; T1[r16 * S8 + c4 + 1] = a1;
            T1[r16 * S8 + c4 + 2] = a2; T1[r16 * S8 + c4 + 3] = a3;
        }
        __syncthreads();

        // stage2: S = T1 @ CT + 0.03 I  [32x32] ; err = y - CM @ mup
        {
            float a0 = 0, a1 = 0;
            const float* pa = T1 + r16 * S8;
#pragma unroll 8
            for (int k = 0; k < ZD; k++) {
                float a = pa[k];
                float2 bv = *(const float2*)&CT[k * S4 + c2];
                a0 += a * bv.x; a1 += a * bv.y;
            }
            if (r16 == c2)     a0 += 0.03f;
            if (r16 == c2 + 1) a1 += 0.03f;
            SS[r16 * S4 + c2] = a0; SS[r16 * S4 + c2 + 1] = a1;
        }
        if (tid < AD) {
            float s = 0.f;
            const float* pc = CM + tid * S8;
#pragma unroll 8
            for (int k = 0; k < ZD; k++) s += pc[k] * mup[k];
            err[tid] = y_s[tid] - s;
        }
        __syncthreads();

        // stage3: wave0: chol32 + trinv32 ; waves2-3: mixC(t+1)
        if (tid < 64) {
            const int lr = lane & 31;
            float rw[32];
#pragma unroll
            for (int k = 0; k < 32; k += 2) {
                float2 v = *(const float2*)&SS[lr * S4 + k];
                rw[k] = v.x; rw[k + 1] = v.y;
            }
#pragma unroll
            for (int j = 0; j < 32; j++) {
                float djj = __shfl(rw[j], j);
                float di = rsqrtf(djj);
                di = di * (1.5f - 0.5f * djj * di * di);
                float l = rw[j] * di;
                Lc[lr] = l;
                if (lane == 0) invd[j] = di;
                if (lane < 32) SS[lr * S4 + j] = l;
#pragma unroll
                for (int q = (j + 1) >> 2; q < 8; q++) {
                    float4 lv = *(const float4*)&Lc[4 * q];
                    int k0 = 4 * q;
                    if (k0 + 0 > j) rw[k0 + 0] -= l * lv.x;
                    if (k0 + 1 > j) rw[k0 + 1] -= l * lv.y;
                    if (k0 + 2 > j) rw[k0 + 2] -= l * lv.z;
                    if (k0 + 3 > j) rw[k0 + 3] -= l * lv.w;
                }
            }
            // trinv32: lane lr owns column lr of TI = L^-1
            float tc[32];
#pragma unroll
            for (int i = 0; i < 32; i++) {
                float di = invd[i];
                float s0 = 0, s1 = 0;
#pragma unroll
                for (int k = 0; k + 2 <= i; k += 2) {
                    float2 lv = *(const float2*)&SS[i * S4 + k];
                    s0 += lv.x * tc[k]; s1 += lv.y * tc[k + 1];
                }
                if (i & 1) s0 += SS[i * S4 + (i - 1)] * tc[i - 1];
                float s = s0 + s1;
                tc[i] = di * (((lr == i) ? 1.0f : 0.0f) - s);
                if (lane < 32) TI[i * S4 + lr] = tc[i];
            }
        } else if (tid >= 128 && tid < 256) {
            if (t < T_ - 1) mixC_part(t + 1);
        }
        __syncthreads();

        // stage4: Z = TI @ T1  [32x64] k=32 ; e2 = TI @ err
        {
            float a0 = 0, a1 = 0, a2 = 0, a3 = 0;
            const float* pa = TI + r16 * S4;
#pragma unroll 8
            for (int k = 0; k < 32; k++) {
                float a = pa[k];
                float4 bv = *(const float4*)&T1[k * S8 + c4];
                a0 += a * bv.x; a1 += a * bv.y; a2 += a * bv.z; a3 += a * bv.w;
            }
            Zm[r16 * S8 + c4 + 0] = a0; Zm[r16 * S8 + c4 + 1] = a1;
            Zm[r16 * S8 + c4 + 2] = a2; Zm[r16 * S8 + c4 + 3] = a3;
        }
        if (tid < 32) {
            float s = 0.f;
            const float* pa = TI + tid * S4;
#pragma unroll
            for (int k = 0; k < 32; k++) s += pa[k] * err[k];
            e2[tid] = s;
        }
        __syncthreads();

        // stage5: sig_f = SP - Z^T Z -> SF & out ; mu_f = mup + Z^T e2 -> muf & out
        {
            float acc[2][4] = {};
            mm64<32, S8, S8, true>(Zm, Zm, acc, r2, c4);
            float* og = osg + (size_t)t * ZD * ZD;
#pragma unroll
            for (int rr = 0; rr < 2; rr++) {
                int r = r2 + rr;
                float4 sp = *(const float4*)&SP[r * S8 + c4];
                float4 v;
                v.x = sp.x - acc[rr][0]; v.y = sp.y - acc[rr][1];
                v.z = sp.z - acc[rr][2]; v.w = sp.w - acc[rr][3];
                *(float4*)&SF[r * S8 + c4] = v;
                *(float4*)(og + r * ZD + c4) = v;
            }
        }
        if (tid < ZD) {
            float s = 0.f;
#pragma unroll
            for (int k = 0; k < 32; k++) s += Zm[k * S8 + tid] * e2[k];
            float v = mup[tid] + s;
            muf[tid] = v;
            omu[t * ZD + tid] = v;
        }
        __syncthreads();

        if (t < T_ - 1) {
            // stage6: M = A(t+1) @ SF
            {
                float acc[2][4] = {};
                mm64<ZD, S8, S8, false>(Am, SF, acc, r2, c4);
#pragma unroll
                for (int rr = 0; rr < 2; rr++) {
                    int r = r2 + rr;
                    *(float4*)&Mm[r * S8 + c4] = make_float4(acc[rr][0], acc[rr][1], acc[rr][2], acc[rr][3]);
                }
            }
            __syncthreads();
            // stage7: SP' = M @ A^T + Q ; mup' = A(t+1) @ muf
            {
                float acc[2][4] = {};
                mm64<ZD, S8, S8, false>(Mm, At, acc, r2, c4);
#pragma unroll
                for (int rr = 0; rr < 2; rr++) {
                    int r = r2 + rr;
#pragma unroll
                    for (int j = 0; j < 4; j++)
                        SP[r * S8 + c4 + j] = acc[rr][j] + ((r == c4 + j) ? 0.08f : 0.0f);
                }
            }
            if (tid >= 448) {
                int i = tid - 448;
                float s = 0.f;
                const float* pa = Am + i * S8;
#pragma unroll 8
                for (int k = 0; k < ZD; k++) s += pa[k] * muf[k];
                mup[i] = s;
            }
            __syncthreads();
        }
    }

    // ================= SMOOTHER INIT =================
    mixA_full(T_ - 1);
#pragma unroll
    for (int rr = 0; rr < 2; rr++) {
        int r = r2 + rr;
#pragma unroll
        for (int j = 0; j < 4; j++) SG[r * S5 + c4 + j] = SF[r * S8 + c4 + j];
    }
    if (tid < ZD) mus[tid] = muf[tid];
    __syncthreads();

    // ================= BACKWARD SMOOTHER =================
    for (int t = T_ - 2; t >= 0; t--) {
        // stage0: load SF(t), muf(t) from out
        {
            const float4* og4 = (const float4*)(osg + (size_t)t * ZD * ZD);
#pragma unroll
            for (int rr = 0; rr < 2; rr++) {
                int r = r2 + rr;
                float4 v = og4[r * 16 + cg];
                *(float4*)&SF[r * S8 + c4] = v;
            }
        }
        if (tid >= 448) muf[tid - 448] = omu[t * ZD + (tid - 448)];
        __syncthreads();

        // stage1: M = A(t+1) @ SF -> Mm
        {
            float acc[2][4] = {};
            mm64<ZD, S8, S8, false>(Am, SF, acc, r2, c4);
#pragma unroll
            for (int rr = 0; rr < 2; rr++) {
                int r = r2 + rr;
                *(float4*)&Mm[r * S8 + c4] = make_float4(acc[rr][0], acc[rr][1], acc[rr][2], acc[rr][3]);
            }
        }
        __syncthreads();

        // stage2: spn = M @ A^T + Q -> SP ; mpn = A @ muf
        {
            float acc[2][4] = {};
            mm64<ZD, S8, S8, false>(Mm, At, acc, r2, c4);
#pragma unroll
            for (int rr = 0; rr < 2; rr++) {
                int r = r2 + rr;
#pragma unroll
                for (int j = 0; j < 4; j++)
                    SP[r * S8 + c4 + j] = acc[rr][j] + ((r == c4 + j) ? 0.08f : 0.0f);
            }
        }
        if (tid >= 448) {
            int i = tid - 448;
            float s = 0.f;
            const float* pa = Am + i * S8;
#pragma unroll 8
            for (int k = 0; k < ZD; k++) s += pa[k] * muf[k];
            mpn[i] = s;
        }
        __syncthreads();

        // stage3: wave0: chol64 + trinv64 ; wave1: dv ; waves4-7: mixA(t)
        if (tid < 64) {
            float rw[64];
#pragma unroll
            for (int k = 0; k < 64; k += 4) {
                float4 v = *(const float4*)&SP[lane * S8 + k];
                rw[k] = v.x; rw[k + 1] = v.y; rw[k + 2] = v.z; rw[k + 3] = v.w;
            }
#pragma unroll
            for (int j = 0; j < 64; j++) {
                float djj = __shfl(rw[j], j);
                float di = rsqrtf(djj);
                di = di * (1.5f - 0.5f * djj * di * di);
                float l = rw[j] * di;
                Lc[lane] = l;
                if (lane == 0) invd[j] = di;
                LB[lane * S8 + j] = l;
#pragma unroll
                for (int q = (j + 1) >> 2; q < 16; q++) {
                    float4 lv = *(const float4*)&Lc[4 * q];
                    int k0 = 4 * q;
                    if (k0 + 0 > j) rw[k0 + 0] -= l * lv.x;
                    if (k0 + 1 > j) rw[k0 + 1] -= l * lv.y;
                    if (k0 + 2 > j) rw[k0 + 2] -= l * lv.z;
                    if (k0 + 3 > j) rw[k0 + 3] -= l * lv.w;
                }
            }
            // trinv64: lane owns column `lane` of T6 = L^-1
            float tc[64];
#pragma unroll
            for (int i = 0; i < 64; i++) {
                float di = invd[i];
                float s0 = 0, s1 = 0, s2 = 0, s3 = 0;
#pragma unroll
                for (int q = 0; q < (i >> 2); q++) {
                    float4 lv = *(const float4*)&LB[i * S8 + 4 * q];
                    s0 += lv.x * tc[4 * q + 0]; s1 += lv.y * tc[4 * q + 1];
                    s2 += lv.z * tc[4 * q + 2]; s3 += lv.w * tc[4 * q + 3];
                }
#pragma unroll
                for (int k = i & ~3; k < i; k++) s0 += LB[i * S8 + k] * tc[k];
                float s = (s0 + s1) + (s2 + s3);
                tc[i] = di * (((lane == i) ? 1.0f : 0.0f) - s);
                T6[i * S5 + lane] = tc[i];
            }
        } else if (tid < 128) {
            int i = tid - 64;
            dv[i] = mus[i] - mpn[i];
        } else if (tid >= 256) {
            if (t > 0) mixA_part(t);
        }
        __syncthreads();

        // stage4: Y = T6 @ M -> LB (chol L dead)
        {
            float acc[2][4] = {};
            mm64<ZD, S5, S8, false>(T6, Mm, acc, r2, c4);
#pragma unroll
            for (int rr = 0; rr < 2; rr++) {
                int r = r2 + rr;
                *(float4*)&LB[r * S8 + c4] = make_float4(acc[rr][0], acc[rr][1], acc[rr][2], acc[rr][3]);
            }
        }
        __syncthreads();

        // stage5: X = T6^T @ Y -> X_
        {
            float acc[2][4] = {};
            mm64<ZD, S5, S8, true>(T6, LB, acc, r2, c4);
#pragma unroll
            for (int rr = 0; rr < 2; rr++) {
                int r = r2 + rr;
                *(float4*)&X_[r * S8 + c4] = make_float4(acc[rr][0], acc[rr][1], acc[rr][2], acc[rr][3]);
            }
        }
        __syncthreads();

        // stage6: V = (SG - SP) @ X -> Mm
        {
            float acc[2][4] = {};
            const float* ps0 = SG + r2 * S5;       const float* pq0 = SP + r2 * S8;
            const float* ps1 = SG + (r2 + 1) * S5; const float* pq1 = SP + (r2 + 1) * S8;
#pragma unroll 8
            for (int k = 0; k < ZD; k++) {
                float aA = ps0[k] - pq0[k];
                float aB = ps1[k] - pq1[k];
                float4 bv = *(const float4*)&X_[k * S8 + c4];
                acc[0][0] += aA * bv.x; acc[0][1] += aA * bv.y; acc[0][2] += aA * bv.z; acc[0][3] += aA * bv.w;
                acc[1][0] += aB * bv.x; acc[1][1] += aB * bv.y; acc[1][2] += aB * bv.z; acc[1][3] += aB * bv.w;
            }
#pragma unroll
            for (int rr = 0; rr < 2; rr++) {
                int r = r2 + rr;
                *(float4*)&Mm[r * S8 + c4] = make_float4(acc[rr][0], acc[rr][1], acc[rr][2], acc[rr][3]);
            }
        }
        __syncthreads();

        // stage7: sig_s = SF + V^T @ X -> SG & out ; mu_s = muf + X^T dv -> mus & out
        {
            float acc[2][4] = {};
            mm64<ZD, S8, S8, true>(Mm, X_, acc, r2, c4);
            float* og = osg + (size_t)t * ZD * ZD;
#pragma unroll
            for (int rr = 0; rr < 2; rr++) {
                int r = r2 + rr;
                float4 sf = *(const float4*)&SF[r * S8 + c4];
                float4 v;
                v.x = sf.x + acc[rr][0]; v.y = sf.y + acc[rr][1];
                v.z = sf.z + acc[rr][2]; v.w = sf.w + acc[rr][3];
                SG[r * S5 + c4 + 0] = v.x; SG[r * S5 + c4 + 1] = v.y;
                SG[r * S5 + c4 + 2] = v.z; SG[r * S5 + c4 + 3] = v.w;
                *(float4*)(og + r * ZD + c4) = v;
            }
        }
        if (tid < ZD) {
            float s = 0.f;
#pragma unroll 8
            for (int k = 0; k < ZD; k++) s += X_[k * S8 + tid] * dv[k];
            float v = muf[tid] + s;
            mus[tid] = v;
            omu[t * ZD + tid] = v;
        }
        __syncthreads();
    }
}

extern "C" void kernel_launch(void* const* d_in, const int* in_sizes, int n_in,
                              void* d_out, int out_size, void* d_ws, size_t ws_size,
                              hipStream_t stream) {
    const float* obs = (const float*)d_in[0];
    const float* lg  = (const float*)d_in[1];
    const float* AK  = (const float*)d_in[2];
    const float* CK  = (const float*)d_in[3];
    (void)d_ws; (void)ws_size; (void)in_sizes; (void)n_in; (void)out_size;
    kvae_kernel<<<dim3(B_), dim3(512), 0, stream>>>(obs, lg, AK, CK, (float*)d_out);
}

// Round 4
// 3978.761 us; speedup vs baseline: 3.9677x; 3.9677x over previous
//
#include <hip/hip_runtime.h>

#define B_ 128
#define T_ 80
#define AD 32
#define ZD 64
#define KD 16
#define S8 68   // stride for 64-col LDS matrices
#define S4 34   // stride for 32-col LDS matrices

// acc[2][4] += op(Pa) @ Qb for rows (r2,r2+1), cols c4..c4+3.
template<int KL, int AS, int BS, bool ATRANS>
__device__ __forceinline__ void mm64(const float* __restrict__ Pa, const float* __restrict__ Qb,
                                     float acc[2][4], int r2, int c4)
{
#pragma unroll 8
    for (int k = 0; k < KL; k++) {
        float aA, aB;
        if (ATRANS) { aA = Pa[k * AS + r2];   aB = Pa[k * AS + r2 + 1]; }
        else        { aA = Pa[r2 * AS + k];   aB = Pa[(r2 + 1) * AS + k]; }
        const float4 bv = *(const float4*)&Qb[k * BS + c4];
        acc[0][0] += aA * bv.x; acc[0][1] += aA * bv.y; acc[0][2] += aA * bv.z; acc[0][3] += aA * bv.w;
        acc[1][0] += aB * bv.x; acc[1][1] += aB * bv.y; acc[1][2] += aB * bv.z; acc[1][3] += aB * bv.w;
    }
}

__global__ __launch_bounds__(512, 2)
void kvae_kernel(const float* __restrict__ obs, const float* __restrict__ logits,
                 const float* __restrict__ AK, const float* __restrict__ CK,
                 float* __restrict__ out)
{
    __shared__ __align__(16) float W[T_ * KD];
    __shared__ __align__(16) float Am[ZD * S8];   // A(t+1)
    __shared__ __align__(16) float At[ZD * S8];   // A(t+1)^T
    __shared__ __align__(16) float SP[ZD * S8];   // sig_p / spn (GJ left, destroyed) / V
    __shared__ __align__(16) float SF[ZD * S8];   // sig_f
    __shared__ __align__(16) float Mm[ZD * S8];   // M
    __shared__ __align__(16) float Pool[9792];
    __shared__ __align__(16) float y_s[32];
    __shared__ __align__(16) float mup[64];
    __shared__ __align__(16) float muf[64];
    __shared__ __align__(16) float mus[64];
    __shared__ __align__(16) float mpn[64];
    __shared__ __align__(16) float dv[64];

    // forward aliases
    float* T1 = Pool;            // [32][68]  C @ sig_p
    float* CM = Pool + 2176;     // [32][68]  C
    float* CT = Pool + 4352;     // [64][34]  C^T
    float* U_ = Pool + 6528;     // [32][68]  GJ right: S^-1 T1 ; col 64 = S^-1 err
    float* S_ = Pool + 8704;     // [32][34]  GJ left
    // backward aliases
    float* Xb = Pool;            // [64][68]  GJ right: X = spn^-1 M
    float* SG = Pool + 4352;     // [64][68]  sig_s carry

    const int tid = threadIdx.x;
    const int b   = blockIdx.x;

    const int r16 = tid >> 4;      // 0..31
    const int cg  = tid & 15;      // 0..15
    const int c4  = cg << 2;       // 0..60
    const int c2  = cg << 1;       // 0..30
    const int r2  = r16 << 1;      // 0..62
    const int i64 = tid >> 3;      // 0..63  (bwd GJ row)
    const int c8  = (tid & 7) << 3; // 0..56 (bwd GJ col group)

    const float* obs_b = obs    + (size_t)b * T_ * AD;
    const float* lg_b  = logits + (size_t)b * T_ * KD;
    float* omu = out + (size_t)b * T_ * ZD;
    float* osg = out + (size_t)B_ * T_ * ZD + (size_t)b * T_ * ZD * ZD;
    const float4* AK4 = (const float4*)AK;
    const float4* CK4 = (const float4*)CK;

    auto mixA_full = [&](int tt) {
#pragma unroll
        for (int rr = 0; rr < 2; rr++) {
            int r = r2 + rr;
            float4 a = make_float4(0.f, 0.f, 0.f, 0.f);
#pragma unroll
            for (int k = 0; k < KD; k++) {
                float wk = W[tt * KD + k];
                float4 v = AK4[k * 1024 + r * 16 + cg];
                a.x += wk * v.x; a.y += wk * v.y; a.z += wk * v.z; a.w += wk * v.w;
            }
            *(float4*)&Am[r * S8 + c4] = a;
            At[(c4 + 0) * S8 + r] = a.x; At[(c4 + 1) * S8 + r] = a.y;
            At[(c4 + 2) * S8 + r] = a.z; At[(c4 + 3) * S8 + r] = a.w;
        }
    };
    auto mixC_full = [&](int tt) {
        float4 a = make_float4(0.f, 0.f, 0.f, 0.f);
#pragma unroll
        for (int k = 0; k < KD; k++) {
            float wk = W[tt * KD + k];
            float4 v = CK4[k * 512 + r16 * 16 + cg];
            a.x += wk * v.x; a.y += wk * v.y; a.z += wk * v.z; a.w += wk * v.w;
        }
        *(float4*)&CM[r16 * S8 + c4] = a;
        CT[(c4 + 0) * S4 + r16] = a.x; CT[(c4 + 1) * S4 + r16] = a.y;
        CT[(c4 + 2) * S4 + r16] = a.z; CT[(c4 + 3) * S4 + r16] = a.w;
    };

    // ---- prologue
    if (tid < T_) {
        float l[KD]; float mx = -1e30f;
#pragma unroll
        for (int k = 0; k < KD; k++) { l[k] = lg_b[tid * KD + k]; mx = fmaxf(mx, l[k]); }
        float s = 0.f;
#pragma unroll
        for (int k = 0; k < KD; k++) { l[k] = expf(l[k] - mx); s += l[k]; }
        float inv = 1.0f / s;
#pragma unroll
        for (int k = 0; k < KD; k++) W[tid * KD + k] = l[k] * inv;
    }
#pragma unroll
    for (int rr = 0; rr < 2; rr++) {
        int r = r2 + rr;
#pragma unroll
        for (int j = 0; j < 4; j++) SP[r * S8 + c4 + j] = (r == c4 + j) ? 20.0f : 0.0f;
    }
    if (tid < ZD) mup[tid] = 0.0f;
    __syncthreads();

    // ================= FORWARD FILTER =================
    for (int t = 0; t < T_; t++) {
        // s0: mix A(t+1), C(t); load y
        if (t < T_ - 1) mixA_full(t + 1);
        mixC_full(t);
        if (tid < AD) y_s[tid] = obs_b[t * AD + tid];
        __syncthreads();

        // s1: T1 = CM @ SP   [32x64] k=64
        {
            float a0 = 0, a1 = 0, a2 = 0, a3 = 0;
            const float* pa = CM + r16 * S8;
#pragma unroll 8
            for (int k = 0; k < ZD; k++) {
                float a = pa[k];
                float4 bv = *(const float4*)&SP[k * S8 + c4];
                a0 += a * bv.x; a1 += a * bv.y; a2 += a * bv.z; a3 += a * bv.w;
            }
            T1[r16 * S8 + c4 + 0] = a0; T1[r16 * S8 + c4 + 1] = a1;
            T1[r16 * S8 + c4 + 2] = a2; T1[r16 * S8 + c4 + 3] = a3;
        }
        __syncthreads();

        // s2: S = T1 @ CT + 0.03 I ; U := T1 (right half, kept in regs) ; err -> U col 64
        float4 ur; float ue = 0.f;
        {
            float a0 = 0, a1 = 0;
            const float* pa = T1 + r16 * S8;
#pragma unroll 8
            for (int k = 0; k < ZD; k++) {
                float a = pa[k];
                float2 bv = *(const float2*)&CT[k * S4 + c2];
                a0 += a * bv.x; a1 += a * bv.y;
            }
            if (r16 == c2)     a0 += 0.03f;
            if (r16 == c2 + 1) a1 += 0.03f;
            S_[r16 * S4 + c2] = a0; S_[r16 * S4 + c2 + 1] = a1;
            ur = *(const float4*)&T1[r16 * S8 + c4];
            if (cg == 15) {
                float s = 0.f;
                const float* pc = CM + r16 * S8;
#pragma unroll 8
                for (int k = 0; k < ZD; k++) s += pc[k] * mup[k];
                ue = y_s[r16] - s;
            }
            if (r16 < 2) {      // publish initial pivot rows
                *(float4*)&U_[r16 * S8 + c4] = ur;
                if (cg == 15) U_[r16 * S8 + 64] = ue;
            }
        }
        __syncthreads();

        // GJ32 on [S_ | U(regs), err]: 16 block-2 pivot steps.
        // With NORMALIZED pivot rows n = Pinv@L, elimination multipliers are (f0,f1).
#pragma unroll 1
        for (int j = 0; j < 16; j++) {
            const int p0 = 2 * j, p1 = p0 + 1;
            const int i = r16;
            // phase A: read everything needed
            const float f0 = S_[i * S4 + p0], f1 = S_[i * S4 + p1];
            const float qa = S_[p0 * S4 + p0], qb = S_[p0 * S4 + p1];
            const float qc = S_[p1 * S4 + p0], qd = S_[p1 * S4 + p1];
            const float l0x = S_[p0 * S4 + c2], l0y = S_[p0 * S4 + c2 + 1];
            const float l1x = S_[p1 * S4 + c2], l1y = S_[p1 * S4 + c2 + 1];
            const float4 r0 = *(const float4*)&U_[p0 * S8 + c4];
            const float4 r1 = *(const float4*)&U_[p1 * S8 + c4];
            float e0 = 0.f, e1 = 0.f;
            if (cg == 15) { e0 = U_[p0 * S8 + 64]; e1 = U_[p1 * S8 + 64]; }
            __syncthreads();
            // phase B: compute + write
            const float dinv = 1.0f / (qa * qd - qb * qc);
            const float i00 =  qd * dinv, i01 = -qb * dinv;
            const float i10 = -qc * dinv, i11 =  qa * dinv;
            const float n0x = i00 * l0x + i01 * l1x, n0y = i00 * l0y + i01 * l1y;
            const float n1x = i10 * l0x + i11 * l1x, n1y = i10 * l0y + i11 * l1y;
            float4 m0, m1;
            m0.x = i00 * r0.x + i01 * r1.x; m0.y = i00 * r0.y + i01 * r1.y;
            m0.z = i00 * r0.z + i01 * r1.z; m0.w = i00 * r0.w + i01 * r1.w;
            m1.x = i10 * r0.x + i11 * r1.x; m1.y = i10 * r0.y + i11 * r1.y;
            m1.z = i10 * r0.z + i11 * r1.z; m1.w = i10 * r0.w + i11 * r1.w;
            const float me0 = i00 * e0 + i01 * e1, me1 = i10 * e0 + i11 * e1;
            if (i == p0) {
                S_[i * S4 + c2] = n0x; S_[i * S4 + c2 + 1] = n0y;
                ur = m0; if (cg == 15) ue = me0;
            } else if (i == p1) {
                S_[i * S4 + c2] = n1x; S_[i * S4 + c2 + 1] = n1y;
                ur = m1; if (cg == 15) ue = me1;
            } else {
                // multipliers = (f0, f1) against normalized pivot rows
                S_[i * S4 + c2]     -= f0 * n0x + f1 * n1x;
                S_[i * S4 + c2 + 1] -= f0 * n0y + f1 * n1y;
                ur.x -= f0 * m0.x + f1 * m1.x; ur.y -= f0 * m0.y + f1 * m1.y;
                ur.z -= f0 * m0.z + f1 * m1.z; ur.w -= f0 * m0.w + f1 * m1.w;
                if (cg == 15) ue -= f0 * me0 + f1 * me1;
            }
            if (j < 15 && (i == p0 + 2 || i == p0 + 3)) {   // publish next pivot rows
                *(float4*)&U_[i * S8 + c4] = ur;
                if (cg == 15) U_[i * S8 + 64] = ue;
            }
            __syncthreads();
        }
        // write back all of U
        *(float4*)&U_[r16 * S8 + c4] = ur;
        if (cg == 15) U_[r16 * S8 + 64] = ue;
        __syncthreads();

        // s3: sig_f = SP - T1^T U -> SF & out ; mu_f = mup + T1^T u -> muf & out
        {
            float acc[2][4] = {};
            mm64<AD, S8, S8, true>(T1, U_, acc, r2, c4);
            float* og = osg + (size_t)t * ZD * ZD;
#pragma unroll
            for (int rr = 0; rr < 2; rr++) {
                int r = r2 + rr;
                float4 sp = *(const float4*)&SP[r * S8 + c4];
                float4 v;
                v.x = sp.x - acc[rr][0]; v.y = sp.y - acc[rr][1];
                v.z = sp.z - acc[rr][2]; v.w = sp.w - acc[rr][3];
                *(float4*)&SF[r * S8 + c4] = v;
                *(float4*)(og + r * ZD + c4) = v;
            }
        }
        if (tid < ZD) {
            float s = 0.f;
#pragma unroll
            for (int k = 0; k < AD; k++) s += T1[k * S8 + tid] * U_[k * S8 + 64];
            float v = mup[tid] + s;
            muf[tid] = v;
            omu[t * ZD + tid] = v;
        }
        __syncthreads();

        if (t < T_ - 1) {
            // s4: M = A(t+1) @ SF
            {
                float acc[2][4] = {};
                mm64<ZD, S8, S8, false>(Am, SF, acc, r2, c4);
#pragma unroll
                for (int rr = 0; rr < 2; rr++)
                    *(float4*)&Mm[(r2 + rr) * S8 + c4] =
                        make_float4(acc[rr][0], acc[rr][1], acc[rr][2], acc[rr][3]);
            }
            __syncthreads();
            // s5: SP' = M @ A^T + Q ; mup' = A(t+1) @ muf
            {
                float acc[2][4] = {};
                mm64<ZD, S8, S8, false>(Mm, At, acc, r2, c4);
#pragma unroll
                for (int rr = 0; rr < 2; rr++) {
                    int r = r2 + rr;
#pragma unroll
                    for (int j = 0; j < 4; j++)
                        SP[r * S8 + c4 + j] = acc[rr][j] + ((r == c4 + j) ? 0.08f : 0.0f);
                }
            }
            if (tid >= 448) {
                int i = tid - 448;
                float s = 0.f;
                const float* pa = Am + i * S8;
#pragma unroll 8
                for (int k = 0; k < ZD; k++) s += pa[k] * muf[k];
                mup[i] = s;
            }
            __syncthreads();
        }
    }

    // ================= SMOOTHER INIT =================
#pragma unroll
    for (int rr = 0; rr < 2; rr++) {
        int r = r2 + rr;
        *(float4*)&SG[r * S8 + c4] = *(const float4*)&SF[r * S8 + c4];
    }
    if (tid < ZD) mus[tid] = muf[tid];
    __syncthreads();

    // ================= BACKWARD SMOOTHER =================
    for (int t = T_ - 2; t >= 0; t--) {
        // s0: mix A(t+1); load SF(t), muf(t) from out
        mixA_full(t + 1);
        {
            const float4* og4 = (const float4*)(osg + (size_t)t * ZD * ZD);
#pragma unroll
            for (int rr = 0; rr < 2; rr++) {
                int r = r2 + rr;
                *(float4*)&SF[r * S8 + c4] = og4[r * 16 + cg];
            }
        }
        if (tid >= 448) muf[tid - 448] = omu[t * ZD + (tid - 448)];
        __syncthreads();

        // s1: M = A(t+1) @ SF -> Mm and Xb ; mpn = A @ muf
        {
            float acc[2][4] = {};
            mm64<ZD, S8, S8, false>(Am, SF, acc, r2, c4);
#pragma unroll
            for (int rr = 0; rr < 2; rr++) {
                int r = r2 + rr;
                float4 v = make_float4(acc[rr][0], acc[rr][1], acc[rr][2], acc[rr][3]);
                *(float4*)&Mm[r * S8 + c4] = v;
                *(float4*)&Xb[r * S8 + c4] = v;
            }
        }
        if (tid >= 448) {
            int i = tid - 448;
            float s = 0.f;
            const float* pa = Am + i * S8;
#pragma unroll 8
            for (int k = 0; k < ZD; k++) s += pa[k] * muf[k];
            mpn[i] = s;
        }
        __syncthreads();

        // s2: spn = M @ A^T + Q -> SP ; dv = mus - mpn
        {
            float acc[2][4] = {};
            mm64<ZD, S8, S8, false>(Mm, At, acc, r2, c4);
#pragma unroll
            for (int rr = 0; rr < 2; rr++) {
                int r = r2 + rr;
#pragma unroll
                for (int j = 0; j < 4; j++)
                    SP[r * S8 + c4 + j] = acc[rr][j] + ((r == c4 + j) ? 0.08f : 0.0f);
            }
        }
        if (tid >= 448) { int i = tid - 448; dv[i] = mus[i] - mpn[i]; }
        __syncthreads();

        // GJ64 on [SP | Xb]: X = spn^-1 M. Own right cells in regs (8 cols/thread).
        float4 xr0 = *(const float4*)&Xb[i64 * S8 + c8];
        float4 xr1 = *(const float4*)&Xb[i64 * S8 + c8 + 4];
#pragma unroll 1
        for (int j = 0; j < 32; j++) {
            const int p0 = 2 * j, p1 = p0 + 1;
            // phase A
            const float f0 = SP[i64 * S8 + p0], f1 = SP[i64 * S8 + p1];
            const float qa = SP[p0 * S8 + p0], qb = SP[p0 * S8 + p1];
            const float qc = SP[p1 * S8 + p0], qd = SP[p1 * S8 + p1];
            const float4 l0a = *(const float4*)&SP[p0 * S8 + c8];
            const float4 l0b = *(const float4*)&SP[p0 * S8 + c8 + 4];
            const float4 l1a = *(const float4*)&SP[p1 * S8 + c8];
            const float4 l1b = *(const float4*)&SP[p1 * S8 + c8 + 4];
            const float4 r0a = *(const float4*)&Xb[p0 * S8 + c8];
            const float4 r0b = *(const float4*)&Xb[p0 * S8 + c8 + 4];
            const float4 r1a = *(const float4*)&Xb[p1 * S8 + c8];
            const float4 r1b = *(const float4*)&Xb[p1 * S8 + c8 + 4];
            const float4 ol0 = *(const float4*)&SP[i64 * S8 + c8];
            const float4 ol1 = *(const float4*)&SP[i64 * S8 + c8 + 4];
            __syncthreads();
            // phase B
            const float dinv = 1.0f / (qa * qd - qb * qc);
            const float i00 =  qd * dinv, i01 = -qb * dinv;
            const float i10 = -qc * dinv, i11 =  qa * dinv;
            float4 nl0a, nl0b, nl1a, nl1b, nr0a, nr0b, nr1a, nr1b;
            nl0a.x = i00*l0a.x + i01*l1a.x; nl0a.y = i00*l0a.y + i01*l1a.y;
            nl0a.z = i00*l0a.z + i01*l1a.z; nl0a.w = i00*l0a.w + i01*l1a.w;
            nl0b.x = i00*l0b.x + i01*l1b.x; nl0b.y = i00*l0b.y + i01*l1b.y;
            nl0b.z = i00*l0b.z + i01*l1b.z; nl0b.w = i00*l0b.w + i01*l1b.w;
            nl1a.x = i10*l0a.x + i11*l1a.x; nl1a.y = i10*l0a.y + i11*l1a.y;
            nl1a.z = i10*l0a.z + i11*l1a.z; nl1a.w = i10*l0a.w + i11*l1a.w;
            nl1b.x = i10*l0b.x + i11*l1b.x; nl1b.y = i10*l0b.y + i11*l1b.y;
            nl1b.z = i10*l0b.z + i11*l1b.z; nl1b.w = i10*l0b.w + i11*l1b.w;
            nr0a.x = i00*r0a.x + i01*r1a.x; nr0a.y = i00*r0a.y + i01*r1a.y;
            nr0a.z = i00*r0a.z + i01*r1a.z; nr0a.w = i00*r0a.w + i01*r1a.w;
            nr0b.x = i00*r0b.x + i01*r1b.x; nr0b.y = i00*r0b.y + i01*r1b.y;
            nr0b.z = i00*r0b.z + i01*r1b.z; nr0b.w = i00*r0b.w + i01*r1b.w;
            nr1a.x = i10*r0a.x + i11*r1a.x; nr1a.y = i10*r0a.y + i11*r1a.y;
            nr1a.z = i10*r0a.z + i11*r1a.z; nr1a.w = i10*r0a.w + i11*r1a.w;
            nr1b.x = i10*r0b.x + i11*r1b.x; nr1b.y = i10*r0b.y + i11*r1b.y;
            nr1b.z = i10*r0b.z + i11*r1b.z; nr1b.w = i10*r0b.w + i11*r1b.w;
            if (i64 == p0) {
                *(float4*)&SP[i64 * S8 + c8]     = nl0a;
                *(float4*)&SP[i64 * S8 + c8 + 4] = nl0b;
                xr0 = nr0a; xr1 = nr0b;
            } else if (i64 == p1) {
                *(float4*)&SP[i64 * S8 + c8]     = nl1a;
                *(float4*)&SP[i64 * S8 + c8 + 4] = nl1b;
                xr0 = nr1a; xr1 = nr1b;
            } else {
                // multipliers = (f0, f1) against normalized pivot rows
                float4 w0 = ol0, w1 = ol1;
                w0.x -= f0*nl0a.x + f1*nl1a.x; w0.y -= f0*nl0a.y + f1*nl1a.y;
                w0.z -= f0*nl0a.z + f1*nl1a.z; w0.w -= f0*nl0a.w + f1*nl1a.w;
                w1.x -= f0*nl0b.x + f1*nl1b.x; w1.y -= f0*nl0b.y + f1*nl1b.y;
                w1.z -= f0*nl0b.z + f1*nl1b.z; w1.w -= f0*nl0b.w + f1*nl1b.w;
                *(float4*)&SP[i64 * S8 + c8]     = w0;
                *(float4*)&SP[i64 * S8 + c8 + 4] = w1;
                xr0.x -= f0*nr0a.x + f1*nr1a.x; xr0.y -= f0*nr0a.y + f1*nr1a.y;
                xr0.z -= f0*nr0a.z + f1*nr1a.z; xr0.w -= f0*nr0a.w + f1*nr1a.w;
                xr1.x -= f0*nr0b.x + f1*nr1b.x; xr1.y -= f0*nr0b.y + f1*nr1b.y;
                xr1.z -= f0*nr0b.z + f1*nr1b.z; xr1.w -= f0*nr0b.w + f1*nr1b.w;
            }
            if (j < 31 && (i64 == p0 + 2 || i64 == p0 + 3)) {   // publish next pivot rows
                *(float4*)&Xb[i64 * S8 + c8]     = xr0;
                *(float4*)&Xb[i64 * S8 + c8 + 4] = xr1;
            }
            __syncthreads();
        }
        *(float4*)&Xb[i64 * S8 + c8]     = xr0;
        *(float4*)&Xb[i64 * S8 + c8 + 4] = xr1;
        __syncthreads();

        // s3: V = SG @ X - M  -> SP
        {
            float acc[2][4] = {};
            mm64<ZD, S8, S8, false>(SG, Xb, acc, r2, c4);
#pragma unroll
            for (int rr = 0; rr < 2; rr++) {
                int r = r2 + rr;
                float4 m = *(const float4*)&Mm[r * S8 + c4];
                SP[r * S8 + c4 + 0] = acc[rr][0] - m.x;
                SP[r * S8 + c4 + 1] = acc[rr][1] - m.y;
                SP[r * S8 + c4 + 2] = acc[rr][2] - m.z;
                SP[r * S8 + c4 + 3] = acc[rr][3] - m.w;
            }
        }
        __syncthreads();

        // s4: sig_s = SF + X^T V -> SG & out ; mu_s = muf + X^T dv -> mus & out
        {
            float acc[2][4] = {};
            mm64<ZD, S8, S8, true>(Xb, SP, acc, r2, c4);
            float* og = osg + (size_t)t * ZD * ZD;
#pragma unroll
            for (int rr = 0; rr < 2; rr++) {
                int r = r2 + rr;
                float4 sf = *(const float4*)&SF[r * S8 + c4];
                float4 v;
                v.x = sf.x + acc[rr][0]; v.y = sf.y + acc[rr][1];
                v.z = sf.z + acc[rr][2]; v.w = sf.w + acc[rr][3];
                *(float4*)&SG[r * S8 + c4] = v;
                *(float4*)(og + r * ZD + c4) = v;
            }
        }
        if (tid < ZD) {
            float s = 0.f;
#pragma unroll 8
            for (int k = 0; k < ZD; k++) s += Xb[k * S8 + tid] * dv[k];
            float v = muf[tid] + s;
            mus[tid] = v;
            omu[t * ZD + tid] = v;
        }
        __syncthreads();
    }
}

extern "C" void kernel_launch(void* const* d_in, const int* in_sizes, int n_in,
                              void* d_out, int out_size, void* d_ws, size_t ws_size,
                              hipStream_t stream) {
    const float* obs = (const float*)d_in[0];
    const float* lg  = (const float*)d_in[1];
    const float* AK  = (const float*)d_in[2];
    const float* CK  = (const float*)d_in[3];
    (void)d_ws; (void)ws_size; (void)in_sizes; (void)n_in; (void)out_size;
    kvae_kernel<<<dim3(B_), dim3(512), 0, stream>>>(obs, lg, AK, CK, (float*)d_out);
}